// Round 10
// baseline (147.668 us; speedup 1.0000x reference)
//
#include <hip/hip_runtime.h>

#define INDIM  256
#define HIDDEN 128
#define OUTD   64
#define CHUNK  8192

typedef short  bf16x8 __attribute__((ext_vector_type(8)));
typedef float  f32x4  __attribute__((ext_vector_type(4)));
typedef float  f32x2  __attribute__((ext_vector_type(2)));
typedef ushort u16x8  __attribute__((ext_vector_type(8)));

__device__ inline ushort f2bf(float f) {
    union { float f; unsigned u; } v; v.f = f;
    unsigned u = v.u;
    unsigned r = (u + 0x7FFFu + ((u >> 16) & 1u)) >> 16;  // RNE
    return (ushort)r;
}
__device__ inline f32x2 fp8x2_dec(int packed) {
    return __builtin_amdgcn_cvt_pk_f32_fp8(packed, false);
}
__device__ inline unsigned char fp8_enc(float v) {
    int pk = __builtin_amdgcn_cvt_pk_fp8_f32(v, v, 0, false);
    return (unsigned char)(pk & 0xFF);
}
// decode 4 packed fp8 (one dword) -> 4 floats
__device__ inline void fp8x4_dec(unsigned d, float& f0, float& f1, float& f2, float& f3) {
    f32x2 lo = __builtin_amdgcn_cvt_pk_f32_fp8((int)d, false);
    f32x2 hi = __builtin_amdgcn_cvt_pk_f32_fp8((int)d, true);
    f0 = lo[0]; f1 = lo[1]; f2 = hi[0]; f3 = hi[1];
}

// ================= K1: per-chunk histograms (non-atomic output) + weight conv ==========
__global__ void k1_hist_conv(const int* __restrict__ dst, int* __restrict__ hist,
                             const float* __restrict__ W1, const float* __restrict__ W2,
                             ushort* __restrict__ W1T, ushort* __restrict__ W2T,
                             int E, int nch) {
    int bid = blockIdx.x, tid = threadIdx.x;
    if (bid < nch) {
        __shared__ int h[256];
        h[tid] = 0;
        __syncthreads();
        int base = bid * CHUNK;
        int cnt = min(CHUNK, E - base);
        for (int i = tid; i < cnt; i += 256) atomicAdd(&h[dst[base + i] >> 8], 1);
        __syncthreads();
        hist[bid * 256 + tid] = h[tid];  // single non-atomic write
    } else {
        int j = bid - nch;
        if (j < 128) {                     // W1: [256][128] -> W1T [128][256]
            int i = j * 256 + tid;
            int k = i / HIDDEN, c = i % HIDDEN;
            W1T[c * INDIM + k] = f2bf(W1[i]);
        } else {                           // W2: [128][64] -> W2T [64][128]
            int i = (j - 128) * 256 + tid;
            if (i < HIDDEN * OUTD) {
                int k = i / OUTD, c = i % OUTD;
                W2T[c * HIDDEN + k] = f2bf(W2[i]);
            }
        }
    }
}

// ================= shared MFMA GEMM body (256 threads, raw fp8 out) ==========
template<int BM, int BN, int WM, int WN, bool AFP32>
__device__ void gemm_body(char* Ab, char* Bb, long m0, const void* Ap,
                          const ushort* __restrict__ BT, unsigned char* __restrict__ C,
                          int M, int K) {
    constexpr int BK  = 64;
    constexpr int FM  = WM / 16, FN = WN / 16;
    constexpr int NWN = BN / WN;
    constexpr int TH  = (BM / WM) * NWN * 64;
    static_assert(TH == 256, "gemm geometry must use 256 threads");
    int tid  = threadIdx.x;
    int lane = tid & 63, w = tid >> 6;
    int wm = w / NWN, wn = w % NWN;
    f32x4 acc[FM][FN] = {};

    for (int kt = 0; kt < K; kt += BK) {
        #pragma unroll
        for (int c = tid; c < BM * BK / 8; c += TH) {
            int row = c / (BK / 8);
            int kc  = (c % (BK / 8)) * 8;
            int off = ((row * BK + kc) * 2) ^ ((row & 7) << 4);
            u16x8 pk = {0, 0, 0, 0, 0, 0, 0, 0};
            long g = m0 + row;
            if (g < M) {
                if (AFP32) {
                    const float* A = (const float*)Ap;
                    float4 v0 = *(const float4*)(A + g * K + kt + kc);
                    float4 v1 = *(const float4*)(A + g * K + kt + kc + 4);
                    pk[0] = f2bf(v0.x); pk[1] = f2bf(v0.y); pk[2] = f2bf(v0.z); pk[3] = f2bf(v0.w);
                    pk[4] = f2bf(v1.x); pk[5] = f2bf(v1.y); pk[6] = f2bf(v1.z); pk[7] = f2bf(v1.w);
                } else {
                    const ushort* A = (const ushort*)Ap;
                    pk = *(const u16x8*)(A + g * K + kt + kc);
                }
            }
            *(u16x8*)(Ab + off) = pk;
        }
        #pragma unroll
        for (int c = tid; c < BN * BK / 8; c += TH) {
            int nn = c / (BK / 8);
            int kc = (c % (BK / 8)) * 8;
            int off = ((nn * BK + kc) * 2) ^ ((nn & 7) << 4);
            *(u16x8*)(Bb + off) = *(const u16x8*)(BT + (long)nn * K + kt + kc);
        }
        __syncthreads();
        #pragma unroll
        for (int kk = 0; kk < BK / 32; ++kk) {
            int kb = kk * 32 + (lane >> 4) * 8;
            bf16x8 af[FM], bfv[FN];
            #pragma unroll
            for (int i = 0; i < FM; ++i) {
                int row = wm * WM + i * 16 + (lane & 15);
                af[i] = *(const bf16x8*)(Ab + (((row * BK + kb) * 2) ^ ((row & 7) << 4)));
            }
            #pragma unroll
            for (int j = 0; j < FN; ++j) {
                int nn = wn * WN + j * 16 + (lane & 15);
                bfv[j] = *(const bf16x8*)(Bb + (((nn * BK + kb) * 2) ^ ((nn & 7) << 4)));
            }
            #pragma unroll
            for (int i = 0; i < FM; ++i)
                #pragma unroll
                for (int j = 0; j < FN; ++j)
                    acc[i][j] = __builtin_amdgcn_mfma_f32_16x16x32_bf16(af[i], bfv[j], acc[i][j], 0, 0, 0);
        }
        __syncthreads();
    }

    #pragma unroll
    for (int i = 0; i < FM; ++i) {
        #pragma unroll
        for (int q = 0; q < 4; ++q) {
            long row = m0 + wm * WM + i * 16 + (lane >> 4) * 4 + q;
            if (row < M) {
                #pragma unroll
                for (int j = 0; j < FN; ++j) {
                    int col = wn * WN + j * 16 + (lane & 15);
                    C[row * BN + col] = fp8_enc(acc[i][j][q]);
                }
            }
        }
    }
}

// ================= K2: block 0 = bucket/cursor scan ; blocks 1.. = gemm1 tiles ==========
__global__ __launch_bounds__(256) void k2_scan_gemm1(
        const int* __restrict__ hist, int* __restrict__ chunkbase,
        int* __restrict__ bkt_off, int* __restrict__ bkt_cnt, int* __restrict__ row_start,
        const float* __restrict__ x, const ushort* __restrict__ W1T,
        unsigned char* __restrict__ g1, int n, int E, int nch) {
    __shared__ alignas(16) char pool[2 * 128 * 64 * 2];  // 32 KB
    if (blockIdx.x == 0) {
        int* s = (int*)pool;
        int tid = threadIdx.x;
        int run = 0;
        for (int c = 0; c < nch; ++c) {
            int t = hist[c * 256 + tid];
            chunkbase[c * 256 + tid] = run;
            run += t;
        }
        bkt_cnt[tid] = run;
        int v = run;
        s[tid] = v;
        __syncthreads();
        for (int off = 1; off < 256; off <<= 1) {
            int t = (tid >= off) ? s[tid - off] : 0;
            __syncthreads();
            s[tid] += t;
            __syncthreads();
        }
        bkt_off[tid] = s[tid] - v;  // exclusive
        if (tid == 0) row_start[n] = E;
    } else {
        gemm_body<128, 128, 64, 64, true>(pool, pool + 128 * 64 * 2,
                                          (long)(blockIdx.x - 1) * 128, x, W1T, g1, n, INDIM);
    }
}

// ================= K3: scatter packed edges (LDS cursors only, no global atomics) ======
__global__ void k3_scatter(const int* __restrict__ src, const int* __restrict__ dst,
                           const int* __restrict__ bkt_off, const int* __restrict__ chunkbase,
                           unsigned* __restrict__ binned, int E) {
    __shared__ int lbase[256];
    __shared__ int lcur[256];
    int ch = blockIdx.x, tid = threadIdx.x;
    lbase[tid] = bkt_off[tid] + chunkbase[ch * 256 + tid];
    lcur[tid] = 0;
    __syncthreads();
    int base = ch * CHUNK;
    int cnt = min(CHUNK, E - base);
    for (int i = tid; i < cnt; i += 256) {
        int e = base + i;
        int d = dst[e];
        int b = d >> 8;
        int r = atomicAdd(&lcur[b], 1);
        binned[lbase[b] + r] = ((unsigned)(d & 255) << 16) | (unsigned)src[e];
    }
}

// ================= K4: per-bucket build (row_start, dinv, csr_src) ==========
__global__ void k4_build(const unsigned* __restrict__ binned, const int* __restrict__ bkt_off,
                         const int* __restrict__ bkt_cnt, int* __restrict__ row_start,
                         float* __restrict__ dinv, int* __restrict__ csr_src, int n) {
    __shared__ int ldeg[256];
    __shared__ int loff[256];
    int b = blockIdx.x, tid = threadIdx.x;
    int base = bkt_off[b], cnt = bkt_cnt[b];
    ldeg[tid] = 0;
    __syncthreads();
    for (int i = tid; i < cnt; i += 256) atomicAdd(&ldeg[binned[base + i] >> 16], 1);
    __syncthreads();
    int v = ldeg[tid];
    loff[tid] = v;
    __syncthreads();
    for (int off = 1; off < 256; off <<= 1) {
        int t = (tid >= off) ? loff[tid - off] : 0;
        __syncthreads();
        loff[tid] += t;
        __syncthreads();
    }
    int excl = loff[tid] - v;
    int node = b * 256 + tid;
    if (node < n) {
        row_start[node] = base + excl;
        dinv[node] = rsqrtf((float)(v + 1));
    }
    __syncthreads();
    loff[tid] = excl;  // reuse as cursor
    __syncthreads();
    for (int i = tid; i < cnt; i += 256) {
        unsigned pk = binned[base + i];
        int pos = atomicAdd(&loff[pk >> 16], 1);
        csr_src[base + pos] = (int)(pk & 0xFFFFu);
    }
}

// ================= K5: agg1, transposed gather (2 edges/load), 4 waves/block ==========
// g1 row = 128 fp8 = 32 dwords. lane: g=lane>>5 (edge slot), q=lane&31 (dword -> feats 4q..4q+3)
__global__ __launch_bounds__(256) void k5_agg1(
        const unsigned* __restrict__ g1u, const int* __restrict__ row_start,
        const int* __restrict__ csr_src, const float* __restrict__ dinv,
        const float* __restrict__ b1, ushort* __restrict__ h1, int n) {
    int node = blockIdx.x * 4 + (threadIdx.x >> 6);
    if (node >= n) return;
    int lane = threadIdx.x & 63;
    int g = lane >> 5, q = lane & 31;
    float dn = dinv[node];
    float a0, a1, a2, a3;
    {   // self loop (group 0 only; group 1 contributes 0)
        float f0, f1, f2, f3;
        fp8x4_dec(g1u[(long)node * 32 + q], f0, f1, f2, f3);
        float ws = (g == 0) ? dn : 0.f;
        a0 = ws * f0; a1 = ws * f1; a2 = ws * f2; a3 = ws * f3;
    }
    int s = row_start[node], e = row_start[node + 1];
    int k = s;
    for (; k + 3 < e; k += 4) {   // 4 edges: 2 loads/lane in flight
        int ia = csr_src[k + g], ib = csr_src[k + 2 + g];
        unsigned da = g1u[(long)ia * 32 + q];
        unsigned db = g1u[(long)ib * 32 + q];
        float wa = dinv[ia], wb = dinv[ib];
        float x0, x1, x2, x3, y0, y1, y2, y3;
        fp8x4_dec(da, x0, x1, x2, x3);
        fp8x4_dec(db, y0, y1, y2, y3);
        a0 += wa * x0 + wb * y0;
        a1 += wa * x1 + wb * y1;
        a2 += wa * x2 + wb * y2;
        a3 += wa * x3 + wb * y3;
    }
    for (; k + 1 < e; k += 2) {   // 2 edges
        int ia = csr_src[k + g];
        unsigned da = g1u[(long)ia * 32 + q];
        float wa = dinv[ia];
        float x0, x1, x2, x3;
        fp8x4_dec(da, x0, x1, x2, x3);
        a0 += wa * x0; a1 += wa * x1; a2 += wa * x2; a3 += wa * x3;
    }
    if (k < e && g == 0) {        // last odd edge
        int ia = csr_src[k];
        unsigned da = g1u[(long)ia * 32 + q];
        float wa = dinv[ia];
        float x0, x1, x2, x3;
        fp8x4_dec(da, x0, x1, x2, x3);
        a0 += wa * x0; a1 += wa * x1; a2 += wa * x2; a3 += wa * x3;
    }
    // reduce the 2 edge groups
    a0 += __shfl_xor(a0, 32);
    a1 += __shfl_xor(a1, 32);
    a2 += __shfl_xor(a2, 32);
    a3 += __shfl_xor(a3, 32);
    if (lane < 32) {              // lane q writes feats 4q..4q+3
        float4 bb = *(const float4*)(b1 + 4 * lane);
        ushort4 r;
        r.x = f2bf(fmaxf(dn * a0 + bb.x, 0.f));
        r.y = f2bf(fmaxf(dn * a1 + bb.y, 0.f));
        r.z = f2bf(fmaxf(dn * a2 + bb.z, 0.f));
        r.w = f2bf(fmaxf(dn * a3 + bb.w, 0.f));
        *(ushort4*)(h1 + (long)node * HIDDEN + 4 * lane) = r;
    }
}

// ================= K6: gemm2 (h1 @ W2 -> raw fp8 g2) ==========
__global__ __launch_bounds__(256) void k6_gemm2(const ushort* __restrict__ h1,
                                                const ushort* __restrict__ W2T,
                                                unsigned char* __restrict__ g2, int n) {
    __shared__ alignas(16) char pool[128 * 64 * 2 + 64 * 64 * 2];  // 24 KB
    gemm_body<128, 64, 64, 32, false>(pool, pool + 128 * 64 * 2,
                                      (long)blockIdx.x * 128, h1, W2T, g2, n, HIDDEN);
}

// ================= K7: agg2, transposed gather (4 edges/load) + epilogue ==========
// g2 row = 64 fp8 = 16 dwords. lane: g=lane>>4 (edge slot), q=lane&15 (dword -> feats 4q..4q+3)
__global__ __launch_bounds__(256) void k7_agg2(
        const unsigned* __restrict__ g2u, const int* __restrict__ row_start,
        const int* __restrict__ csr_src, const float* __restrict__ dinv,
        const float* __restrict__ b2, const float* __restrict__ We,
        const float* __restrict__ be, const float* __restrict__ Wg,
        const float* __restrict__ bg, const float* __restrict__ rule_w,
        float* __restrict__ out, int n) {
    int node = blockIdx.x * 4 + (threadIdx.x >> 6);
    if (node >= n) return;
    int lane = threadIdx.x & 63;
    int g = lane >> 4, q = lane & 15;
    float dn = dinv[node];
    float a0, a1, a2, a3;
    {
        float f0, f1, f2, f3;
        fp8x4_dec(g2u[(long)node * 16 + q], f0, f1, f2, f3);
        float ws = (g == 0) ? dn : 0.f;
        a0 = ws * f0; a1 = ws * f1; a2 = ws * f2; a3 = ws * f3;
    }
    int s = row_start[node], e = row_start[node + 1];
    int k = s;
    for (; k + 7 < e; k += 8) {   // 8 edges: 2 loads/lane in flight
        int ia = csr_src[k + g], ib = csr_src[k + 4 + g];
        unsigned da = g2u[(long)ia * 16 + q];
        unsigned db = g2u[(long)ib * 16 + q];
        float wa = dinv[ia], wb = dinv[ib];
        float x0, x1, x2, x3, y0, y1, y2, y3;
        fp8x4_dec(da, x0, x1, x2, x3);
        fp8x4_dec(db, y0, y1, y2, y3);
        a0 += wa * x0 + wb * y0;
        a1 += wa * x1 + wb * y1;
        a2 += wa * x2 + wb * y2;
        a3 += wa * x3 + wb * y3;
    }
    for (; k + 3 < e; k += 4) {   // 4 edges
        int ia = csr_src[k + g];
        unsigned da = g2u[(long)ia * 16 + q];
        float wa = dinv[ia];
        float x0, x1, x2, x3;
        fp8x4_dec(da, x0, x1, x2, x3);
        a0 += wa * x0; a1 += wa * x1; a2 += wa * x2; a3 += wa * x3;
    }
    int rem = e - k;              // 0..3 leftover edges
    if (g < rem) {
        int ia = csr_src[k + g];
        unsigned da = g2u[(long)ia * 16 + q];
        float wa = dinv[ia];
        float x0, x1, x2, x3;
        fp8x4_dec(da, x0, x1, x2, x3);
        a0 += wa * x0; a1 += wa * x1; a2 += wa * x2; a3 += wa * x3;
    }
    // reduce the 4 edge groups (16-lane stripes)
    a0 += __shfl_xor(a0, 32); a0 += __shfl_xor(a0, 16);
    a1 += __shfl_xor(a1, 32); a1 += __shfl_xor(a1, 16);
    a2 += __shfl_xor(a2, 32); a2 += __shfl_xor(a2, 16);
    a3 += __shfl_xor(a3, 32); a3 += __shfl_xor(a3, 16);
    // h2 for feats 4q..4q+3 (duplicated in all 4 groups)
    int f0i = 4 * q;
    float t0 = dn * a0 + b2[f0i + 0];
    float t1 = dn * a1 + b2[f0i + 1];
    float t2 = dn * a2 + b2[f0i + 2];
    float t3 = dn * a3 + b2[f0i + 3];
    // rule_out: 3 dots over 64 feats; partial over own 4 feats, reduce within 16-lane group
    float p0 = t0 * We[(f0i + 0) * 3 + 0] + t1 * We[(f0i + 1) * 3 + 0]
             + t2 * We[(f0i + 2) * 3 + 0] + t3 * We[(f0i + 3) * 3 + 0];
    float p1 = t0 * We[(f0i + 0) * 3 + 1] + t1 * We[(f0i + 1) * 3 + 1]
             + t2 * We[(f0i + 2) * 3 + 1] + t3 * We[(f0i + 3) * 3 + 1];
    float p2 = t0 * We[(f0i + 0) * 3 + 2] + t1 * We[(f0i + 1) * 3 + 2]
             + t2 * We[(f0i + 2) * 3 + 2] + t3 * We[(f0i + 3) * 3 + 2];
    #pragma unroll
    for (int m = 8; m >= 1; m >>= 1) {
        p0 += __shfl_xor(p0, m);
        p1 += __shfl_xor(p1, m);
        p2 += __shfl_xor(p2, m);
    }
    float z = (p0 + be[0]) * Wg[0] + (p1 + be[1]) * Wg[1] + (p2 + be[2]) * Wg[2] + bg[0];
    float gate = 1.f / (1.f + expf(-z));
    float gr = gate * rule_w[0];
    t0 += gr; t1 += gr; t2 += gr; t3 += gr;
    // log_softmax over 64 feats
    float mx = fmaxf(fmaxf(t0, t1), fmaxf(t2, t3));
    #pragma unroll
    for (int m = 8; m >= 1; m >>= 1) mx = fmaxf(mx, __shfl_xor(mx, m));
    float ss = expf(t0 - mx) + expf(t1 - mx) + expf(t2 - mx) + expf(t3 - mx);
    #pragma unroll
    for (int m = 8; m >= 1; m >>= 1) ss += __shfl_xor(ss, m);
    float lg = mx + logf(ss);
    if (lane < 16) {
        float4 o;
        o.x = t0 - lg; o.y = t1 - lg; o.z = t2 - lg; o.w = t3 - lg;
        *(float4*)(out + (long)node * OUTD + f0i) = o;
    }
}

// ======================= launcher (7 dispatches) =======================
extern "C" void kernel_launch(void* const* d_in, const int* in_sizes, int n_in,
                              void* d_out, int out_size, void* d_ws, size_t ws_size,
                              hipStream_t stream) {
    const float* x   = (const float*)d_in[0];
    const int*   ei  = (const int*)d_in[1];
    const float* W1  = (const float*)d_in[3];
    const float* b1  = (const float*)d_in[4];
    const float* W2  = (const float*)d_in[5];
    const float* b2  = (const float*)d_in[6];
    const float* We  = (const float*)d_in[7];
    const float* be  = (const float*)d_in[8];
    const float* Wg  = (const float*)d_in[9];
    const float* bg  = (const float*)d_in[10];
    const float* rw  = (const float*)d_in[11];
    float* out = (float*)d_out;

    int n = out_size / OUTD;        // 50000
    int E = in_sizes[1] / 2;        // 800000
    const int* srcv = ei;
    const int* dstv = ei + E;
    int nch = (E + CHUNK - 1) / CHUNK;  // 98

    // ---- carve workspace ----
    char* w = (char*)d_ws;
    size_t off = 0;
    auto carve = [&](size_t bytes) -> void* {
        void* p = w + off;
        off += (bytes + 255) & ~(size_t)255;
        return p;
    };
    int*           hist      = (int*)carve((size_t)nch * 256 * 4);
    int*           chunkbase = (int*)carve((size_t)nch * 256 * 4);
    int*           bkt_off_  = (int*)carve(256 * 4);
    int*           bkt_cnt   = (int*)carve(256 * 4);
    int*           row_start = (int*)carve((size_t)(n + 1) * 4);
    float*         dinv      = (float*)carve((size_t)n * 4);
    unsigned*      binned    = (unsigned*)carve((size_t)E * 4);
    int*           csr_src   = (int*)carve((size_t)E * 4);
    unsigned char* g1        = (unsigned char*)carve((size_t)n * HIDDEN);
    ushort*        h1        = (ushort*)carve((size_t)n * HIDDEN * 2);
    ushort*        W1T       = (ushort*)carve((size_t)HIDDEN * INDIM * 2);
    ushort*        W2T       = (ushort*)carve((size_t)OUTD * HIDDEN * 2);
    unsigned char* g2        = g1;  // reuse: g1 dead after agg1

    k1_hist_conv<<<nch + 160, 256, 0, stream>>>(dstv, hist, W1, W2, W1T, W2T, E, nch);
    k2_scan_gemm1<<<1 + (n + 127) / 128, 256, 0, stream>>>(
        hist, chunkbase, bkt_off_, bkt_cnt, row_start, x, W1T, g1, n, E, nch);
    k3_scatter<<<nch, 256, 0, stream>>>(srcv, dstv, bkt_off_, chunkbase, binned, E);
    k4_build<<<(n + 255) / 256, 256, 0, stream>>>(binned, bkt_off_, bkt_cnt,
                                                  row_start, dinv, csr_src, n);
    k5_agg1<<<(n + 3) / 4, 256, 0, stream>>>((const unsigned*)g1, row_start, csr_src,
                                             dinv, b1, h1, n);
    k6_gemm2<<<(n + 127) / 128, 256, 0, stream>>>(h1, W2T, g2, n);
    k7_agg2<<<(n + 3) / 4, 256, 0, stream>>>((const unsigned*)g2, row_start, csr_src,
                                             dinv, b2, We, be, Wg, bg, rw, out, n);
}